// Round 4
// baseline (15758.508 us; speedup 1.0000x reference)
//
#include <hip/hip_runtime.h>
#include <stdint.h>

#define HID 1024
#define G4  4096
#define BB  64

typedef short short8v __attribute__((ext_vector_type(8)));
typedef float float4v __attribute__((ext_vector_type(4)));
typedef float float16v __attribute__((ext_vector_type(16)));
typedef unsigned long long ull;

static __device__ __forceinline__ unsigned short f2bf(float f) {
    unsigned u = __builtin_bit_cast(unsigned, f);
    u += 0x7fffu + ((u >> 16) & 1u);
    return (unsigned short)(u >> 16);
}
static __device__ __forceinline__ float bf2f(unsigned short s) {
    unsigned u = ((unsigned)s) << 16;
    return __builtin_bit_cast(float, u);
}
static __device__ __forceinline__ float sigm(float x) { return 1.0f / (1.0f + __expf(-x)); }
static __device__ __forceinline__ float tanh_fast(float x) { return 2.0f / (1.0f + __expf(-2.0f * x)) - 1.0f; }

// ---------------- prep: bf16 converts + unit-major reorder + offsets ----------------
__global__ void prep_kernel(const float* __restrict__ data,
                            const int* __restrict__ bs_raw,
                            const float* __restrict__ Wih, const float* __restrict__ Whh,
                            const float* __restrict__ bih, const float* __restrict__ bhh,
                            const float* __restrict__ h0,
                            unsigned short* __restrict__ xb,
                            unsigned short* __restrict__ wih_r,
                            unsigned short* __restrict__ whh_r,
                            float* __restrict__ bias_r,
                            unsigned short* __restrict__ hb0, unsigned short* __restrict__ hb1,
                            int* __restrict__ bs_n, int* __restrict__ offs,
                            unsigned* __restrict__ bar,
                            int total, int T)
{
    int bid = blockIdx.x, tid = threadIdx.x;
    if (bid == 0) {
        __shared__ int sbs[1024];
        bool is64 = (T > 1) && (bs_raw[1] == 0);   // int64 batch_sizes => low word at 2*t
        for (int t = tid; t < T && t < 1024; t += 256) sbs[t] = is64 ? bs_raw[2 * t] : bs_raw[t];
        __syncthreads();
        if (tid == 0) {
            int acc = 0;
            for (int t = 0; t < T; ++t) { bs_n[t] = sbs[t]; offs[t] = acc; acc += sbs[t]; }
            bar[0] = 0u;
        }
        return;
    }
    long N0 = (long)total * (HID / 4);
    long N1 = N0 + (long)G4 * (HID / 4);
    long N2 = N1 + (long)G4 * (HID / 4);
    long N3 = N2 + G4;
    long N4 = N3 + BB * (HID / 4);
    long stride = (long)(gridDim.x - 1) * 256;
    for (long i = (long)(bid - 1) * 256 + tid; i < N4; i += stride) {
        if (i < N0) {
            float4 d = ((const float4*)data)[i];
            ((ushort4*)xb)[i] = make_ushort4(f2bf(d.x), f2bf(d.y), f2bf(d.z), f2bf(d.w));
        } else if (i < N1) {
            long j = i - N0; int r = (int)(j >> 8); int k4 = (int)(j & 255);
            int u = r >> 2, g = r & 3;
            float4 d = ((const float4*)Wih)[(long)(g * HID + u) * (HID / 4) + k4];
            ((ushort4*)wih_r)[j] = make_ushort4(f2bf(d.x), f2bf(d.y), f2bf(d.z), f2bf(d.w));
        } else if (i < N2) {
            long j = i - N1; int r = (int)(j >> 8); int k4 = (int)(j & 255);
            int u = r >> 2, g = r & 3;
            float4 d = ((const float4*)Whh)[(long)(g * HID + u) * (HID / 4) + k4];
            ((ushort4*)whh_r)[j] = make_ushort4(f2bf(d.x), f2bf(d.y), f2bf(d.z), f2bf(d.w));
        } else if (i < N3) {
            int r = (int)(i - N2); int u = r >> 2, g = r & 3;
            bias_r[r] = bih[g * HID + u] + bhh[g * HID + u];
        } else {
            long j = i - N3;
            float4 d = ((const float4*)h0)[j];
            ushort4 o = make_ushort4(f2bf(d.x), f2bf(d.y), f2bf(d.z), f2bf(d.w));
            ((ushort4*)hb0)[j] = o;
            ((ushort4*)hb1)[j] = o;
        }
    }
}

// ---------------- input GEMM: gI = xb @ wih_r^T  (bf16 out) ----------------
__global__ __launch_bounds__(256) void gemm_kernel(const unsigned short* __restrict__ xb,
                                                   const unsigned short* __restrict__ wr,
                                                   unsigned short* __restrict__ gI)
{
    __shared__ unsigned short As[128 * 32];
    __shared__ unsigned short Bs[128 * 32];
    int tid = threadIdx.x;
    int l = tid & 63;
    int w = tid >> 6;
    int m = l & 15, q = l >> 4;
    int mtile = blockIdx.x, ntile = blockIdx.y;

    const unsigned short* pa = xb + (long)(mtile * 128 + (tid >> 2)) * HID + (tid & 3) * 8;
    const unsigned short* pb = wr + (long)(ntile * 128 + (tid >> 2)) * HID + (tid & 3) * 8;
    unsigned short* la = As + (tid >> 2) * 32 + (tid & 3) * 8;
    unsigned short* lb = Bs + (tid >> 2) * 32 + (tid & 3) * 8;

    int RM = (w >> 1) * 64, CN = (w & 1) * 64;
    float4v acc[4][4];
#pragma unroll
    for (int i = 0; i < 4; ++i)
#pragma unroll
        for (int j = 0; j < 4; ++j) acc[i][j] = (float4v){0.f, 0.f, 0.f, 0.f};

    for (int kt = 0; kt < HID; kt += 32) {
        short8v a0 = *(const short8v*)(pa + kt);
        short8v a1 = *(const short8v*)(pa + 64 * HID + kt);
        short8v b0 = *(const short8v*)(pb + kt);
        short8v b1 = *(const short8v*)(pb + 64 * HID + kt);
        __syncthreads();
        *(short8v*)la = a0;
        *(short8v*)(la + 64 * 32) = a1;
        *(short8v*)lb = b0;
        *(short8v*)(lb + 64 * 32) = b1;
        __syncthreads();
        short8v av[4], bv[4];
#pragma unroll
        for (int i = 0; i < 4; ++i) av[i] = *(const short8v*)&As[(RM + i * 16 + m) * 32 + q * 8];
#pragma unroll
        for (int j = 0; j < 4; ++j) bv[j] = *(const short8v*)&Bs[(CN + j * 16 + m) * 32 + q * 8];
#pragma unroll
        for (int i = 0; i < 4; ++i)
#pragma unroll
            for (int j = 0; j < 4; ++j)
                acc[i][j] = __builtin_amdgcn_mfma_f32_16x16x32_bf16(av[i], bv[j], acc[i][j], 0, 0, 0);
    }
#pragma unroll
    for (int i = 0; i < 4; ++i)
#pragma unroll
        for (int j = 0; j < 4; ++j)
#pragma unroll
            for (int r = 0; r < 4; ++r) {
                int grow = mtile * 128 + RM + i * 16 + q * 4 + r;
                int gcol = ntile * 128 + CN + j * 16 + m;
                gI[(long)grow * G4 + gcol] = f2bf(acc[i][j][r]);
            }
}

// ---------------- persistent recurrent kernel ----------------
// 64 blocks x 512 threads (8 waves). Block bid owns hidden units [bid*16,+16)
// = reordered gate rows [bid*64,+64). Wave w: ks = w&1 (K half),
// ug2 = (w>>1)&1 (32-gate-row half), bg = w>>2 (32-batch half).
// 32x32x16 MFMA: D = W_tile(32 gate rows) x h^T(32 batches), K=512 per wave.
// => W L2 stream 262KB/step (2x, was 4x), hlds reads 262KB/step (2x).
// ks1 waves write partials to sg; ks0 keep theirs in registers, read sg,
// finish in-register (C layout: lane l&31=batch, acc[4j+g] = gate g of
// unit 2j + (l>>5)).
// Publish/out use hi-shuffle pairing so stores are 16B/8B contiguous.
__global__ __launch_bounds__(512) void lstm_kernel(
    const unsigned short* __restrict__ gI,
    const unsigned short* __restrict__ whh_r,
    const float* __restrict__ bias_r,
    unsigned short* __restrict__ hb0, unsigned short* __restrict__ hb1,
    const float* __restrict__ h0, const float* __restrict__ c0,
    const int* __restrict__ bs_n, const int* __restrict__ offs,
    unsigned* __restrict__ bar,
    float* __restrict__ out, float* __restrict__ hf, float* __restrict__ cf,
    int T)
{
    __shared__ unsigned short hlds[64 * 1032];   // staged h, 129-slot16 pitch (odd -> b128 conflict-free)
    __shared__ float sg[64 * 68];                // ks1 partial gates
    __shared__ int sbs[1024], soff[1024];

    int tid = threadIdx.x, bid = blockIdx.x;
    int lane = tid & 63;
    int w = tid >> 6;             // wave 0..7
    int lo5 = lane & 31, hi = lane >> 5;
    int ks = w & 1, ug2 = (w >> 1) & 1, bg = w >> 2;

    for (int i = tid; i < T && i < 1024; i += 512) { sbs[i] = bs_n[i]; soff[i] = offs[i]; }

    int b = bg * 32 + lo5;              // batch this lane owns (C col)
    int cu0 = bid * 16 + ug2 * 8;       // first unit of this wave's 8-unit group
    // lane's 4 units: u' = 2j + hi  (j=0..3), global col cu0 + u'
    float c_reg[4], h_reg[4];
    float4 bia[4];
#pragma unroll
    for (int j = 0; j < 4; ++j) {
        int cu = cu0 + 2 * j + hi;
        c_reg[j] = c0[b * HID + cu];
        h_reg[j] = h0[b * HID + cu];
        bia[j] = *(const float4*)&bias_r[cu * 4];
    }

    // A (W) fragment base: gate rows [bid*64 + ug2*32, +32), K half ks
    const unsigned short* wp = whh_r + (size_t)(bid * 64 + ug2 * 32 + lo5) * HID + ks * 512 + hi * 8;
    // B (h^T) fragment base: staged h rows [bg*32, +32), K half ks
    const unsigned short* hp = hlds + (bg * 32 + lo5) * 1032 + ks * 512 + hi * 8;
    // sg slot shared by the (bg,ug2) job pair
    float* sgp = sg + (bg * 32 + lo5) * 68 + ug2 * 32 + 4 * hi;

    __syncthreads();

    // gI prefetch pipeline (ks0 lanes): gv = step t, gvn = step t+1
    ushort4 gv[4] = {};
    if (ks == 0) {
        int bs0 = sbs[0];
        if (b < bs0) {
#pragma unroll
            for (int j = 0; j < 4; ++j)
                gv[j] = *(const ushort4*)(gI + (size_t)(soff[0] + b) * G4 + (cu0 + 2 * j + hi) * 4);
        }
    }

    for (int t = 0; t < T; ++t) {
        const ull* hq = (const ull*)((t & 1) ? hb1 : hb0);
        ull* hn = (ull*)((t & 1) ? hb0 : hb1);
        int bs = sbs[t], off = soff[t];
        int bsn = (t + 1 < T) ? sbs[t + 1] : 0;
        int offn = (t + 1 < T) ? soff[t + 1] : 0;

        // stage h (128KB) into LDS: coalesced agent-scope 8B loads, all in flight
        {
            ull st[32];
#pragma unroll
            for (int it = 0; it < 16; ++it) {
                size_t idx = (size_t)it * 512 + tid;      // 16B-chunk index
                st[2 * it]     = __hip_atomic_load(hq + 2 * idx,     __ATOMIC_RELAXED, __HIP_MEMORY_SCOPE_AGENT);
                st[2 * it + 1] = __hip_atomic_load(hq + 2 * idx + 1, __ATOMIC_RELAXED, __HIP_MEMORY_SCOPE_AGENT);
            }
#pragma unroll
            for (int it = 0; it < 16; ++it) {
                int idx = it * 512 + tid;
                int row = idx >> 7, slot = idx & 127;
                union { ull u2[2]; short8v s8; } v;
                v.u2[0] = st[2 * it]; v.u2[1] = st[2 * it + 1];
                *(short8v*)(hlds + row * 1032 + slot * 8) = v.s8;
            }
        }
        __syncthreads();   // [A] hlds ready

        // prefetch next step's gI slice (hides under MFMA phase)
        ushort4 gvn[4] = {};
        if (ks == 0 && b < bsn) {
#pragma unroll
            for (int j = 0; j < 4; ++j)
                gvn[j] = *(const ushort4*)(gI + (size_t)(offn + b) * G4 + (cu0 + 2 * j + hi) * 4);
        }

        // partial gates over this wave's K half: 32x32x16 MFMA chain
        float16v acc;
#pragma unroll
        for (int r = 0; r < 16; ++r) acc[r] = 0.f;
#pragma unroll 8
        for (int kk = 0; kk < 32; ++kk) {
            short8v av = *(const short8v*)(wp + kk * 16);
            short8v bv = *(const short8v*)(hp + kk * 16);
            acc = __builtin_amdgcn_mfma_f32_32x32x16_bf16(av, bv, acc, 0, 0, 0);
        }

        if (ks == 1) {
            // write partial to sg: float4 per j at col ug2*32 + j*8 + 4*hi
#pragma unroll
            for (int j = 0; j < 4; ++j) {
                float4 v = make_float4(acc[4 * j], acc[4 * j + 1], acc[4 * j + 2], acc[4 * j + 3]);
                *(float4*)(sgp + j * 8) = v;
            }
        }
        __syncthreads();   // [B] sg ready (also: all hlds reads done)

        if (ks == 0) {
            bool act = (b < bs);
            bool retire = act && (t + 1 >= T || b >= bsn);
#pragma unroll
            for (int j = 0; j < 4; ++j) {
                float4 p = *(const float4*)(sgp + j * 8);
                int cu = cu0 + 2 * j + hi;
                if (act) {
                    float gi = acc[4 * j + 0] + p.x + bia[j].x + bf2f(gv[j].x);
                    float gf = acc[4 * j + 1] + p.y + bia[j].y + bf2f(gv[j].y);
                    float gg = acc[4 * j + 2] + p.z + bia[j].z + bf2f(gv[j].z);
                    float go = acc[4 * j + 3] + p.w + bia[j].w + bf2f(gv[j].w);
                    float fi = sigm(gi), ff = sigm(gf), fg = tanh_fast(gg), fo = sigm(go);
                    c_reg[j] = ff * c_reg[j] + fi * fg;
                    h_reg[j] = fo * tanh_fast(c_reg[j]);
                    if (retire) {
                        hf[b * HID + cu] = h_reg[j];
                        cf[b * HID + cu] = c_reg[j];
                    }
                }
                gv[j] = gvn[j];
            }
            // out: pair units via hi-shuffle -> 8B contiguous float2 stores
            if (act) {
                float* orow = out + (size_t)(off + b) * HID + cu0;
#pragma unroll
                for (int j = 0; j < 4; ++j) {
                    float pv = __shfl_xor(h_reg[j], 32);
                    if (hi == 0) {
                        float2 o2 = make_float2(h_reg[j], pv);
                        *(float2*)(orow + 2 * j) = o2;
                    }
                }
            }
            // publish h: pack (own, partner) bf16 pairs -> 2x 8B contiguous agent stores
            {
                unsigned wd[4];
#pragma unroll
                for (int j = 0; j < 4; ++j) {
                    float pv = __shfl_xor(h_reg[j], 32);
                    wd[j] = (unsigned)f2bf(h_reg[j]) | ((unsigned)f2bf(pv) << 16);
                }
                if (hi == 0) {
                    size_t base = (size_t)b * 256 + bid * 4 + ug2 * 2;
                    ull pk0 = (ull)wd[0] | ((ull)wd[1] << 32);
                    ull pk1 = (ull)wd[2] | ((ull)wd[3] << 32);
                    __hip_atomic_store(hn + base,     pk0, __ATOMIC_RELAXED, __HIP_MEMORY_SCOPE_AGENT);
                    __hip_atomic_store(hn + base + 1, pk1, __ATOMIC_RELAXED, __HIP_MEMORY_SCOPE_AGENT);
                }
            }
        }

        if (t + 1 < T) {
            asm volatile("s_waitcnt vmcnt(0)" ::: "memory");   // publishes drained to IC
            __syncthreads();   // [C] whole block's h published
            if (tid == 0) {
                __hip_atomic_fetch_add(bar, 1u, __ATOMIC_RELAXED, __HIP_MEMORY_SCOPE_AGENT);
                unsigned tgt = (unsigned)(t + 1) * 64u;
                while (__hip_atomic_load(bar, __ATOMIC_RELAXED, __HIP_MEMORY_SCOPE_AGENT) < tgt)
                    __builtin_amdgcn_s_sleep(1);
            }
            __syncthreads();   // [D] released (single poller + block fan-out)
        }
    }
}

extern "C" void kernel_launch(void* const* d_in, const int* in_sizes, int n_in,
                              void* d_out, int out_size, void* d_ws, size_t ws_size,
                              hipStream_t stream)
{
    const float* data = (const float*)d_in[0];
    const int* bs_raw = (const int*)d_in[1];
    const float* Wih = (const float*)d_in[2];
    const float* Whh = (const float*)d_in[3];
    const float* bih = (const float*)d_in[4];
    const float* bhh = (const float*)d_in[5];
    const float* h0 = (const float*)d_in[6];
    const float* c0 = (const float*)d_in[7];
    int total = in_sizes[0] / HID;     // 47872
    int T = in_sizes[1];               // 1000

    char* p = (char*)d_ws;
    unsigned short* gI = (unsigned short*)p;     p += (size_t)total * G4 * 2;
    unsigned short* xb = (unsigned short*)p;     p += (size_t)total * HID * 2;
    unsigned short* wih_r = (unsigned short*)p;  p += (size_t)G4 * HID * 2;
    unsigned short* whh_r = (unsigned short*)p;  p += (size_t)G4 * HID * 2;
    float* bias_r = (float*)p;                   p += (size_t)G4 * 4;
    unsigned short* hbuf0 = (unsigned short*)p;  p += (size_t)BB * HID * 2;
    unsigned short* hbuf1 = (unsigned short*)p;  p += (size_t)BB * HID * 2;
    int* bs_n = (int*)p;                         p += 4096;
    int* offs = (int*)p;                         p += 4096;
    unsigned* bar = (unsigned*)p;                p += 256;

    float* out = (float*)d_out;
    float* hf = out + (size_t)total * HID;
    float* cf = hf + (size_t)BB * HID;

    prep_kernel<<<4097, 256, 0, stream>>>(data, bs_raw, Wih, Whh, bih, bhh, h0,
                                          xb, wih_r, whh_r, bias_r, hbuf0, hbuf1,
                                          bs_n, offs, bar, total, T);
    gemm_kernel<<<dim3(total / 128, G4 / 128), 256, 0, stream>>>(xb, wih_r, gI);
    lstm_kernel<<<64, 512, 0, stream>>>(gI, whh_r, bias_r, hbuf0, hbuf1, h0, c0,
                                        bs_n, offs, bar, out, hf, cf, T);
}

// Round 5
// 14746.419 us; speedup vs baseline: 1.0686x; 1.0686x over previous
//
#include <hip/hip_runtime.h>
#include <stdint.h>

#define HID 1024
#define G4  4096
#define BB  64

typedef short short8v __attribute__((ext_vector_type(8)));
typedef float float4v __attribute__((ext_vector_type(4)));
typedef float float16v __attribute__((ext_vector_type(16)));
typedef unsigned long long ull;

static __device__ __forceinline__ unsigned short f2bf(float f) {
    unsigned u = __builtin_bit_cast(unsigned, f);
    u += 0x7fffu + ((u >> 16) & 1u);
    return (unsigned short)(u >> 16);
}
static __device__ __forceinline__ float bf2f(unsigned short s) {
    unsigned u = ((unsigned)s) << 16;
    return __builtin_bit_cast(float, u);
}
static __device__ __forceinline__ float sigm(float x) { return 1.0f / (1.0f + __expf(-x)); }
static __device__ __forceinline__ float tanh_fast(float x) { return 2.0f / (1.0f + __expf(-2.0f * x)) - 1.0f; }

// ---------------- prep: bf16 converts + unit-major reorder + offsets ----------------
__global__ void prep_kernel(const float* __restrict__ data,
                            const int* __restrict__ bs_raw,
                            const float* __restrict__ Wih, const float* __restrict__ Whh,
                            const float* __restrict__ bih, const float* __restrict__ bhh,
                            const float* __restrict__ h0,
                            unsigned short* __restrict__ xb,
                            unsigned short* __restrict__ wih_r,
                            unsigned short* __restrict__ whh_r,
                            float* __restrict__ bias_r,
                            unsigned short* __restrict__ hb0, unsigned short* __restrict__ hb1,
                            int* __restrict__ bs_n, int* __restrict__ offs,
                            unsigned* __restrict__ bar,
                            int total, int T)
{
    int bid = blockIdx.x, tid = threadIdx.x;
    if (bid == 0) {
        __shared__ int sbs[1024];
        bool is64 = (T > 1) && (bs_raw[1] == 0);   // int64 batch_sizes => low word at 2*t
        for (int t = tid; t < T && t < 1024; t += 256) sbs[t] = is64 ? bs_raw[2 * t] : bs_raw[t];
        // zero the sync region: 64 flag lines (32 dwords apart) + release line
        for (int i = tid; i < 2112; i += 256) bar[i] = 0u;
        __syncthreads();
        if (tid == 0) {
            int acc = 0;
            for (int t = 0; t < T; ++t) { bs_n[t] = sbs[t]; offs[t] = acc; acc += sbs[t]; }
        }
        return;
    }
    long N0 = (long)total * (HID / 4);
    long N1 = N0 + (long)G4 * (HID / 4);
    long N2 = N1 + (long)G4 * (HID / 4);
    long N3 = N2 + G4;
    long N4 = N3 + BB * (HID / 4);
    long stride = (long)(gridDim.x - 1) * 256;
    for (long i = (long)(bid - 1) * 256 + tid; i < N4; i += stride) {
        if (i < N0) {
            float4 d = ((const float4*)data)[i];
            ((ushort4*)xb)[i] = make_ushort4(f2bf(d.x), f2bf(d.y), f2bf(d.z), f2bf(d.w));
        } else if (i < N1) {
            long j = i - N0; int r = (int)(j >> 8); int k4 = (int)(j & 255);
            int u = r >> 2, g = r & 3;
            float4 d = ((const float4*)Wih)[(long)(g * HID + u) * (HID / 4) + k4];
            ((ushort4*)wih_r)[j] = make_ushort4(f2bf(d.x), f2bf(d.y), f2bf(d.z), f2bf(d.w));
        } else if (i < N2) {
            long j = i - N1; int r = (int)(j >> 8); int k4 = (int)(j & 255);
            int u = r >> 2, g = r & 3;
            float4 d = ((const float4*)Whh)[(long)(g * HID + u) * (HID / 4) + k4];
            ((ushort4*)whh_r)[j] = make_ushort4(f2bf(d.x), f2bf(d.y), f2bf(d.z), f2bf(d.w));
        } else if (i < N3) {
            int r = (int)(i - N2); int u = r >> 2, g = r & 3;
            bias_r[r] = bih[g * HID + u] + bhh[g * HID + u];
        } else {
            long j = i - N3;
            float4 d = ((const float4*)h0)[j];
            ushort4 o = make_ushort4(f2bf(d.x), f2bf(d.y), f2bf(d.z), f2bf(d.w));
            ((ushort4*)hb0)[j] = o;
            ((ushort4*)hb1)[j] = o;
        }
    }
}

// ---------------- input GEMM: gI = xb @ wih_r^T  (bf16 out) ----------------
__global__ __launch_bounds__(256) void gemm_kernel(const unsigned short* __restrict__ xb,
                                                   const unsigned short* __restrict__ wr,
                                                   unsigned short* __restrict__ gI)
{
    __shared__ unsigned short As[128 * 32];
    __shared__ unsigned short Bs[128 * 32];
    int tid = threadIdx.x;
    int l = tid & 63;
    int w = tid >> 6;
    int m = l & 15, q = l >> 4;
    int mtile = blockIdx.x, ntile = blockIdx.y;

    const unsigned short* pa = xb + (long)(mtile * 128 + (tid >> 2)) * HID + (tid & 3) * 8;
    const unsigned short* pb = wr + (long)(ntile * 128 + (tid >> 2)) * HID + (tid & 3) * 8;
    unsigned short* la = As + (tid >> 2) * 32 + (tid & 3) * 8;
    unsigned short* lb = Bs + (tid >> 2) * 32 + (tid & 3) * 8;

    int RM = (w >> 1) * 64, CN = (w & 1) * 64;
    float4v acc[4][4];
#pragma unroll
    for (int i = 0; i < 4; ++i)
#pragma unroll
        for (int j = 0; j < 4; ++j) acc[i][j] = (float4v){0.f, 0.f, 0.f, 0.f};

    for (int kt = 0; kt < HID; kt += 32) {
        short8v a0 = *(const short8v*)(pa + kt);
        short8v a1 = *(const short8v*)(pa + 64 * HID + kt);
        short8v b0 = *(const short8v*)(pb + kt);
        short8v b1 = *(const short8v*)(pb + 64 * HID + kt);
        __syncthreads();
        *(short8v*)la = a0;
        *(short8v*)(la + 64 * 32) = a1;
        *(short8v*)lb = b0;
        *(short8v*)(lb + 64 * 32) = b1;
        __syncthreads();
        short8v av[4], bv[4];
#pragma unroll
        for (int i = 0; i < 4; ++i) av[i] = *(const short8v*)&As[(RM + i * 16 + m) * 32 + q * 8];
#pragma unroll
        for (int j = 0; j < 4; ++j) bv[j] = *(const short8v*)&Bs[(CN + j * 16 + m) * 32 + q * 8];
#pragma unroll
        for (int i = 0; i < 4; ++i)
#pragma unroll
            for (int j = 0; j < 4; ++j)
                acc[i][j] = __builtin_amdgcn_mfma_f32_16x16x32_bf16(av[i], bv[j], acc[i][j], 0, 0, 0);
    }
#pragma unroll
    for (int i = 0; i < 4; ++i)
#pragma unroll
        for (int j = 0; j < 4; ++j)
#pragma unroll
            for (int r = 0; r < 4; ++r) {
                int grow = mtile * 128 + RM + i * 16 + q * 4 + r;
                int gcol = ntile * 128 + CN + j * 16 + m;
                gI[(long)grow * G4 + gcol] = f2bf(acc[i][j][r]);
            }
}

// ---------------- persistent recurrent kernel ----------------
// Identical compute structure to round 4 (32x32x16 MFMA, 2-way K split,
// 8 waves, zero bank conflicts). ONLY the inter-block barrier changed:
//
//   round-4: fetch_add + 64 pollers mixing RMW+loads on ONE IC line
//            -> RMW serialization against the poll stream (~10us/step)
//   round-5: flag-array barrier. Arrival = one agent store to the block's
//            OWN 128B-strided flag line (no serialization). Block 0 wave 0
//            polls all 64 flags with one 64-lane vector load; on __all()
//            success stores a release word on a separate line. 63 blocks
//            poll the release word READ-ONLY. No line mixes RMW + polling.
__global__ __launch_bounds__(512) void lstm_kernel(
    const unsigned short* __restrict__ gI,
    const unsigned short* __restrict__ whh_r,
    const float* __restrict__ bias_r,
    unsigned short* __restrict__ hb0, unsigned short* __restrict__ hb1,
    const float* __restrict__ h0, const float* __restrict__ c0,
    const int* __restrict__ bs_n, const int* __restrict__ offs,
    unsigned* __restrict__ bar,
    float* __restrict__ out, float* __restrict__ hf, float* __restrict__ cf,
    int T)
{
    __shared__ unsigned short hlds[64 * 1032];   // staged h (odd 16B-slot pitch -> b128 conflict-free)
    __shared__ float sg[64 * 68];                // ks1 partial gates
    __shared__ int sbs[1024], soff[1024];

    int tid = threadIdx.x, bid = blockIdx.x;
    int lane = tid & 63;
    int w = tid >> 6;             // wave 0..7
    int lo5 = lane & 31, hi = lane >> 5;
    int ks = w & 1, ug2 = (w >> 1) & 1, bg = w >> 2;

    unsigned* flags = bar;               // flag line for block b at dword b*32 (128B stride)
    unsigned* rel = bar + 2048;          // release word, own line

    for (int i = tid; i < T && i < 1024; i += 512) { sbs[i] = bs_n[i]; soff[i] = offs[i]; }

    int b = bg * 32 + lo5;              // batch this lane owns (C col)
    int cu0 = bid * 16 + ug2 * 8;       // first unit of this wave's 8-unit group
    float c_reg[4], h_reg[4];
    float4 bia[4];
#pragma unroll
    for (int j = 0; j < 4; ++j) {
        int cu = cu0 + 2 * j + hi;
        c_reg[j] = c0[b * HID + cu];
        h_reg[j] = h0[b * HID + cu];
        bia[j] = *(const float4*)&bias_r[cu * 4];
    }

    // A (W) fragment base: gate rows [bid*64 + ug2*32, +32), K half ks
    const unsigned short* wp = whh_r + (size_t)(bid * 64 + ug2 * 32 + lo5) * HID + ks * 512 + hi * 8;
    // B (h^T) fragment base: staged h rows [bg*32, +32), K half ks
    const unsigned short* hp = hlds + (bg * 32 + lo5) * 1032 + ks * 512 + hi * 8;
    // sg slot shared by the (bg,ug2) job pair
    float* sgp = sg + (bg * 32 + lo5) * 68 + ug2 * 32 + 4 * hi;

    __syncthreads();

    // gI prefetch pipeline (ks0 lanes): gv = step t, gvn = step t+1
    ushort4 gv[4] = {};
    if (ks == 0) {
        int bs0 = sbs[0];
        if (b < bs0) {
#pragma unroll
            for (int j = 0; j < 4; ++j)
                gv[j] = *(const ushort4*)(gI + (size_t)(soff[0] + b) * G4 + (cu0 + 2 * j + hi) * 4);
        }
    }

    for (int t = 0; t < T; ++t) {
        const ull* hq = (const ull*)((t & 1) ? hb1 : hb0);
        ull* hn = (ull*)((t & 1) ? hb0 : hb1);
        int bs = sbs[t], off = soff[t];
        int bsn = (t + 1 < T) ? sbs[t + 1] : 0;
        int offn = (t + 1 < T) ? soff[t + 1] : 0;

        // stage h (128KB) into LDS: coalesced agent-scope 8B loads, all in flight
        {
            ull st[32];
#pragma unroll
            for (int it = 0; it < 16; ++it) {
                size_t idx = (size_t)it * 512 + tid;      // 16B-chunk index
                st[2 * it]     = __hip_atomic_load(hq + 2 * idx,     __ATOMIC_RELAXED, __HIP_MEMORY_SCOPE_AGENT);
                st[2 * it + 1] = __hip_atomic_load(hq + 2 * idx + 1, __ATOMIC_RELAXED, __HIP_MEMORY_SCOPE_AGENT);
            }
#pragma unroll
            for (int it = 0; it < 16; ++it) {
                int idx = it * 512 + tid;
                int row = idx >> 7, slot = idx & 127;
                union { ull u2[2]; short8v s8; } v;
                v.u2[0] = st[2 * it]; v.u2[1] = st[2 * it + 1];
                *(short8v*)(hlds + row * 1032 + slot * 8) = v.s8;
            }
        }
        __syncthreads();   // [A] hlds ready

        // prefetch next step's gI slice (hides under MFMA phase)
        ushort4 gvn[4] = {};
        if (ks == 0 && b < bsn) {
#pragma unroll
            for (int j = 0; j < 4; ++j)
                gvn[j] = *(const ushort4*)(gI + (size_t)(offn + b) * G4 + (cu0 + 2 * j + hi) * 4);
        }

        // partial gates over this wave's K half: 32x32x16 MFMA chain
        float16v acc;
#pragma unroll
        for (int r = 0; r < 16; ++r) acc[r] = 0.f;
#pragma unroll 8
        for (int kk = 0; kk < 32; ++kk) {
            short8v av = *(const short8v*)(wp + kk * 16);
            short8v bv = *(const short8v*)(hp + kk * 16);
            acc = __builtin_amdgcn_mfma_f32_32x32x16_bf16(av, bv, acc, 0, 0, 0);
        }

        if (ks == 1) {
#pragma unroll
            for (int j = 0; j < 4; ++j) {
                float4 v = make_float4(acc[4 * j], acc[4 * j + 1], acc[4 * j + 2], acc[4 * j + 3]);
                *(float4*)(sgp + j * 8) = v;
            }
        }
        __syncthreads();   // [B] sg ready (also: all hlds reads done)

        if (ks == 0) {
            bool act = (b < bs);
            bool retire = act && (t + 1 >= T || b >= bsn);
#pragma unroll
            for (int j = 0; j < 4; ++j) {
                float4 p = *(const float4*)(sgp + j * 8);
                int cu = cu0 + 2 * j + hi;
                if (act) {
                    float gi = acc[4 * j + 0] + p.x + bia[j].x + bf2f(gv[j].x);
                    float gf = acc[4 * j + 1] + p.y + bia[j].y + bf2f(gv[j].y);
                    float gg = acc[4 * j + 2] + p.z + bia[j].z + bf2f(gv[j].z);
                    float go = acc[4 * j + 3] + p.w + bia[j].w + bf2f(gv[j].w);
                    float fi = sigm(gi), ff = sigm(gf), fg = tanh_fast(gg), fo = sigm(go);
                    c_reg[j] = ff * c_reg[j] + fi * fg;
                    h_reg[j] = fo * tanh_fast(c_reg[j]);
                    if (retire) {
                        hf[b * HID + cu] = h_reg[j];
                        cf[b * HID + cu] = c_reg[j];
                    }
                }
                gv[j] = gvn[j];
            }
            // out: pair units via hi-shuffle -> 8B contiguous float2 stores
            if (act) {
                float* orow = out + (size_t)(off + b) * HID + cu0;
#pragma unroll
                for (int j = 0; j < 4; ++j) {
                    float pv = __shfl_xor(h_reg[j], 32);
                    if (hi == 0) {
                        float2 o2 = make_float2(h_reg[j], pv);
                        *(float2*)(orow + 2 * j) = o2;
                    }
                }
            }
            // publish h: pack (own, partner) bf16 pairs -> 2x 8B agent stores
            {
                unsigned wd[4];
#pragma unroll
                for (int j = 0; j < 4; ++j) {
                    float pv = __shfl_xor(h_reg[j], 32);
                    wd[j] = (unsigned)f2bf(h_reg[j]) | ((unsigned)f2bf(pv) << 16);
                }
                if (hi == 0) {
                    size_t base = (size_t)b * 256 + bid * 4 + ug2 * 2;
                    ull pk0 = (ull)wd[0] | ((ull)wd[1] << 32);
                    ull pk1 = (ull)wd[2] | ((ull)wd[3] << 32);
                    __hip_atomic_store(hn + base,     pk0, __ATOMIC_RELAXED, __HIP_MEMORY_SCOPE_AGENT);
                    __hip_atomic_store(hn + base + 1, pk1, __ATOMIC_RELAXED, __HIP_MEMORY_SCOPE_AGENT);
                }
            }
        }

        if (t + 1 < T) {
            asm volatile("s_waitcnt vmcnt(0)" ::: "memory");   // this thread's publishes drained to IC
            __syncthreads();   // [C] whole block's h published
            unsigned tgt = (unsigned)(t + 1);
            if (bid == 0) {
                if (w == 0) {
                    if (tid == 0)
                        __hip_atomic_store(&flags[0], tgt, __ATOMIC_RELAXED, __HIP_MEMORY_SCOPE_AGENT);
                    // 64 lanes poll 64 flag lines with one vector load per round
                    for (;;) {
                        unsigned v = __hip_atomic_load(&flags[lane * 32],
                                                       __ATOMIC_RELAXED, __HIP_MEMORY_SCOPE_AGENT);
                        if (__all((int)(v >= tgt))) break;
                        __builtin_amdgcn_s_sleep(2);
                    }
                    if (tid == 0)
                        __hip_atomic_store(rel, tgt, __ATOMIC_RELAXED, __HIP_MEMORY_SCOPE_AGENT);
                }
            } else {
                if (tid == 0) {
                    __hip_atomic_store(&flags[bid * 32], tgt, __ATOMIC_RELAXED, __HIP_MEMORY_SCOPE_AGENT);
                    // read-only poll of the release line
                    while (__hip_atomic_load(rel, __ATOMIC_RELAXED, __HIP_MEMORY_SCOPE_AGENT) < tgt)
                        __builtin_amdgcn_s_sleep(2);
                }
            }
            __syncthreads();   // [D] released (block fan-out)
        }
    }
}

extern "C" void kernel_launch(void* const* d_in, const int* in_sizes, int n_in,
                              void* d_out, int out_size, void* d_ws, size_t ws_size,
                              hipStream_t stream)
{
    const float* data = (const float*)d_in[0];
    const int* bs_raw = (const int*)d_in[1];
    const float* Wih = (const float*)d_in[2];
    const float* Whh = (const float*)d_in[3];
    const float* bih = (const float*)d_in[4];
    const float* bhh = (const float*)d_in[5];
    const float* h0 = (const float*)d_in[6];
    const float* c0 = (const float*)d_in[7];
    int total = in_sizes[0] / HID;     // 47872
    int T = in_sizes[1];               // 1000

    char* p = (char*)d_ws;
    unsigned short* gI = (unsigned short*)p;     p += (size_t)total * G4 * 2;
    unsigned short* xb = (unsigned short*)p;     p += (size_t)total * HID * 2;
    unsigned short* wih_r = (unsigned short*)p;  p += (size_t)G4 * HID * 2;
    unsigned short* whh_r = (unsigned short*)p;  p += (size_t)G4 * HID * 2;
    float* bias_r = (float*)p;                   p += (size_t)G4 * 4;
    unsigned short* hbuf0 = (unsigned short*)p;  p += (size_t)BB * HID * 2;
    unsigned short* hbuf1 = (unsigned short*)p;  p += (size_t)BB * HID * 2;
    int* bs_n = (int*)p;                         p += 4096;
    int* offs = (int*)p;                         p += 4096;
    unsigned* bar = (unsigned*)p;                p += 16384;   // 64 flag lines + release line

    float* out = (float*)d_out;
    float* hf = out + (size_t)total * HID;
    float* cf = hf + (size_t)BB * HID;

    prep_kernel<<<4097, 256, 0, stream>>>(data, bs_raw, Wih, Whh, bih, bhh, h0,
                                          xb, wih_r, whh_r, bias_r, hbuf0, hbuf1,
                                          bs_n, offs, bar, total, T);
    gemm_kernel<<<dim3(total / 128, G4 / 128), 256, 0, stream>>>(xb, wih_r, gI);
    lstm_kernel<<<64, 512, 0, stream>>>(gI, whh_r, bias_r, hbuf0, hbuf1, h0, c0,
                                        bs_n, offs, bar, out, hf, cf, T);
}

// Round 6
// 13491.476 us; speedup vs baseline: 1.1680x; 1.0930x over previous
//
#include <hip/hip_runtime.h>
#include <stdint.h>

#define HID 1024
#define G4  4096
#define BB  64

typedef short short8v __attribute__((ext_vector_type(8)));
typedef int   int4v   __attribute__((ext_vector_type(4)));
typedef float float4v __attribute__((ext_vector_type(4)));
typedef float float16v __attribute__((ext_vector_type(16)));
typedef unsigned long long ull;

static __device__ __forceinline__ unsigned short f2bf(float f) {
    unsigned u = __builtin_bit_cast(unsigned, f);
    u += 0x7fffu + ((u >> 16) & 1u);
    return (unsigned short)(u >> 16);
}
static __device__ __forceinline__ float bf2f(unsigned short s) {
    unsigned u = ((unsigned)s) << 16;
    return __builtin_bit_cast(float, u);
}
static __device__ __forceinline__ float sigm(float x) { return 1.0f / (1.0f + __expf(-x)); }
static __device__ __forceinline__ float tanh_fast(float x) { return 2.0f / (1.0f + __expf(-2.0f * x)) - 1.0f; }

// IC-coherent 16B load/store (bypass L1+L2, served at the coherence point).
// Plain (non-atomic) is sufficient: single writer per location, barrier-ordered.
static __device__ __forceinline__ void ic_load16(const void* p, int4v& d) {
    asm volatile("global_load_dwordx4 %0, %1, off sc0 sc1" : "=v"(d) : "v"(p) : "memory");
}
static __device__ __forceinline__ void ic_store16(void* p, int4v d) {
    asm volatile("global_store_dwordx4 %0, %1, off sc0 sc1" :: "v"(p), "v"(d) : "memory");
}

// ---------------- prep: bf16 converts + unit-major reorder + offsets ----------------
__global__ void prep_kernel(const float* __restrict__ data,
                            const int* __restrict__ bs_raw,
                            const float* __restrict__ Wih, const float* __restrict__ Whh,
                            const float* __restrict__ bih, const float* __restrict__ bhh,
                            const float* __restrict__ h0,
                            unsigned short* __restrict__ xb,
                            unsigned short* __restrict__ wih_r,
                            unsigned short* __restrict__ whh_r,
                            float* __restrict__ bias_r,
                            unsigned short* __restrict__ hb0, unsigned short* __restrict__ hb1,
                            int* __restrict__ bs_n, int* __restrict__ offs,
                            unsigned* __restrict__ bar,
                            int total, int T)
{
    int bid = blockIdx.x, tid = threadIdx.x;
    if (bid == 0) {
        __shared__ int sbs[1024];
        bool is64 = (T > 1) && (bs_raw[1] == 0);   // int64 batch_sizes => low word at 2*t
        for (int t = tid; t < T && t < 1024; t += 256) sbs[t] = is64 ? bs_raw[2 * t] : bs_raw[t];
        // zero the sync region: 64 flag lines (32 dwords apart)
        for (int i = tid; i < 2112; i += 256) bar[i] = 0u;
        __syncthreads();
        if (tid == 0) {
            int acc = 0;
            for (int t = 0; t < T; ++t) { bs_n[t] = sbs[t]; offs[t] = acc; acc += sbs[t]; }
        }
        return;
    }
    long N0 = (long)total * (HID / 4);
    long N1 = N0 + (long)G4 * (HID / 4);
    long N2 = N1 + (long)G4 * (HID / 4);
    long N3 = N2 + G4;
    long N4 = N3 + BB * (HID / 4);
    long stride = (long)(gridDim.x - 1) * 256;
    for (long i = (long)(bid - 1) * 256 + tid; i < N4; i += stride) {
        if (i < N0) {
            float4 d = ((const float4*)data)[i];
            ((ushort4*)xb)[i] = make_ushort4(f2bf(d.x), f2bf(d.y), f2bf(d.z), f2bf(d.w));
        } else if (i < N1) {
            long j = i - N0; int r = (int)(j >> 8); int k4 = (int)(j & 255);
            int u = r >> 2, g = r & 3;
            float4 d = ((const float4*)Wih)[(long)(g * HID + u) * (HID / 4) + k4];
            ((ushort4*)wih_r)[j] = make_ushort4(f2bf(d.x), f2bf(d.y), f2bf(d.z), f2bf(d.w));
        } else if (i < N2) {
            long j = i - N1; int r = (int)(j >> 8); int k4 = (int)(j & 255);
            int u = r >> 2, g = r & 3;
            float4 d = ((const float4*)Whh)[(long)(g * HID + u) * (HID / 4) + k4];
            ((ushort4*)whh_r)[j] = make_ushort4(f2bf(d.x), f2bf(d.y), f2bf(d.z), f2bf(d.w));
        } else if (i < N3) {
            int r = (int)(i - N2); int u = r >> 2, g = r & 3;
            bias_r[r] = bih[g * HID + u] + bhh[g * HID + u];
        } else {
            long j = i - N3;
            float4 d = ((const float4*)h0)[j];
            ushort4 o = make_ushort4(f2bf(d.x), f2bf(d.y), f2bf(d.z), f2bf(d.w));
            ((ushort4*)hb0)[j] = o;
            ((ushort4*)hb1)[j] = o;
        }
    }
}

// ---------------- input GEMM: gI = xb @ wih_r^T  (bf16 out) ----------------
__global__ __launch_bounds__(256) void gemm_kernel(const unsigned short* __restrict__ xb,
                                                   const unsigned short* __restrict__ wr,
                                                   unsigned short* __restrict__ gI)
{
    __shared__ unsigned short As[128 * 32];
    __shared__ unsigned short Bs[128 * 32];
    int tid = threadIdx.x;
    int l = tid & 63;
    int w = tid >> 6;
    int m = l & 15, q = l >> 4;
    int mtile = blockIdx.x, ntile = blockIdx.y;

    const unsigned short* pa = xb + (long)(mtile * 128 + (tid >> 2)) * HID + (tid & 3) * 8;
    const unsigned short* pb = wr + (long)(ntile * 128 + (tid >> 2)) * HID + (tid & 3) * 8;
    unsigned short* la = As + (tid >> 2) * 32 + (tid & 3) * 8;
    unsigned short* lb = Bs + (tid >> 2) * 32 + (tid & 3) * 8;

    int RM = (w >> 1) * 64, CN = (w & 1) * 64;
    float4v acc[4][4];
#pragma unroll
    for (int i = 0; i < 4; ++i)
#pragma unroll
        for (int j = 0; j < 4; ++j) acc[i][j] = (float4v){0.f, 0.f, 0.f, 0.f};

    for (int kt = 0; kt < HID; kt += 32) {
        short8v a0 = *(const short8v*)(pa + kt);
        short8v a1 = *(const short8v*)(pa + 64 * HID + kt);
        short8v b0 = *(const short8v*)(pb + kt);
        short8v b1 = *(const short8v*)(pb + 64 * HID + kt);
        __syncthreads();
        *(short8v*)la = a0;
        *(short8v*)(la + 64 * 32) = a1;
        *(short8v*)lb = b0;
        *(short8v*)(lb + 64 * 32) = b1;
        __syncthreads();
        short8v av[4], bv[4];
#pragma unroll
        for (int i = 0; i < 4; ++i) av[i] = *(const short8v*)&As[(RM + i * 16 + m) * 32 + q * 8];
#pragma unroll
        for (int j = 0; j < 4; ++j) bv[j] = *(const short8v*)&Bs[(CN + j * 16 + m) * 32 + q * 8];
#pragma unroll
        for (int i = 0; i < 4; ++i)
#pragma unroll
            for (int j = 0; j < 4; ++j)
                acc[i][j] = __builtin_amdgcn_mfma_f32_16x16x32_bf16(av[i], bv[j], acc[i][j], 0, 0, 0);
    }
#pragma unroll
    for (int i = 0; i < 4; ++i)
#pragma unroll
        for (int j = 0; j < 4; ++j)
#pragma unroll
            for (int r = 0; r < 4; ++r) {
                int grow = mtile * 128 + RM + i * 16 + q * 4 + r;
                int gcol = ntile * 128 + CN + j * 16 + m;
                gI[(long)grow * G4 + gcol] = f2bf(acc[i][j][r]);
            }
}

// ---------------- persistent recurrent kernel ----------------
// Compute structure identical to rounds 4/5 (32x32x16 MFMA, 2-way K split,
// 8 waves, zero bank conflicts). Round-6 changes attack IC transaction
// density + chain depth ONLY:
//  1. h staging: 16B global_load_dwordx4 sc0 sc1 (dense 1KB/wave-instr,
//     half the IC transactions of the old 8B-atomic stride-16B pattern)
//  2. publish: one 16B sc0sc1 store per hi==0 lane (was 2x 8B atomics)
//  3. barrier: arrive = store own flag line; EVERY block's wave 0 polls all
//     64 flag lines directly (read-only) -> no release hop (saves 2 IC RTTs)
//  4. out/hf/cf stores moved AFTER the flag store -> overlap the poll wait
//     instead of sitting inside the vmcnt(0) drain
__global__ __launch_bounds__(512) void lstm_kernel(
    const unsigned short* __restrict__ gI,
    const unsigned short* __restrict__ whh_r,
    const float* __restrict__ bias_r,
    unsigned short* __restrict__ hb0, unsigned short* __restrict__ hb1,
    const float* __restrict__ h0, const float* __restrict__ c0,
    const int* __restrict__ bs_n, const int* __restrict__ offs,
    unsigned* __restrict__ bar,
    float* __restrict__ out, float* __restrict__ hf, float* __restrict__ cf,
    int T)
{
    __shared__ unsigned short hlds[64 * 1032];   // staged h (odd 16B-slot pitch -> b128 conflict-free)
    __shared__ float sg[64 * 68];                // ks1 partial gates
    __shared__ int sbs[1024], soff[1024];

    int tid = threadIdx.x, bid = blockIdx.x;
    int lane = tid & 63;
    int w = tid >> 6;             // wave 0..7
    int lo5 = lane & 31, hi = lane >> 5;
    int ks = w & 1, ug2 = (w >> 1) & 1, bg = w >> 2;

    unsigned* flags = bar;        // flag line for block b at dword b*32 (128B stride)

    for (int i = tid; i < T && i < 1024; i += 512) { sbs[i] = bs_n[i]; soff[i] = offs[i]; }

    int b = bg * 32 + lo5;              // batch this lane owns (C col)
    int cu0 = bid * 16 + ug2 * 8;       // first unit of this wave's 8-unit group
    float c_reg[4], h_reg[4];
    float4 bia[4];
#pragma unroll
    for (int j = 0; j < 4; ++j) {
        int cu = cu0 + 2 * j + hi;
        c_reg[j] = c0[b * HID + cu];
        h_reg[j] = h0[b * HID + cu];
        bia[j] = *(const float4*)&bias_r[cu * 4];
    }

    // A (W) fragment base: gate rows [bid*64 + ug2*32, +32), K half ks
    const unsigned short* wp = whh_r + (size_t)(bid * 64 + ug2 * 32 + lo5) * HID + ks * 512 + hi * 8;
    // B (h^T) fragment base: staged h rows [bg*32, +32), K half ks
    const unsigned short* hp = hlds + (bg * 32 + lo5) * 1032 + ks * 512 + hi * 8;
    // sg slot shared by the (bg,ug2) job pair
    float* sgp = sg + (bg * 32 + lo5) * 68 + ug2 * 32 + 4 * hi;

    __syncthreads();

    // gI prefetch pipeline (ks0 lanes): gv = step t, gvn = step t+1
    ushort4 gv[4] = {};
    if (ks == 0) {
        int bs0 = sbs[0];
        if (b < bs0) {
#pragma unroll
            for (int j = 0; j < 4; ++j)
                gv[j] = *(const ushort4*)(gI + (size_t)(soff[0] + b) * G4 + (cu0 + 2 * j + hi) * 4);
        }
    }

    for (int t = 0; t < T; ++t) {
        const char* hq8 = (const char*)((t & 1) ? hb1 : hb0) + (size_t)tid * 16;
        char* hn8 = (char*)((t & 1) ? hb0 : hb1);
        int bs = sbs[t], off = soff[t];
        int bsn = (t + 1 < T) ? sbs[t + 1] : 0;
        int offn = (t + 1 < T) ? soff[t + 1] : 0;

        // stage h (128KB) into LDS: 16 dense 16B IC loads per thread, all in flight
        {
            int4v st[16];
#pragma unroll
            for (int it = 0; it < 16; ++it)
                ic_load16(hq8 + (size_t)it * 8192, st[it]);
            asm volatile("s_waitcnt vmcnt(0)" ::: "memory");
            __builtin_amdgcn_sched_barrier(0);
#pragma unroll
            for (int it = 0; it < 16; ++it) {
                int idx = it * 512 + tid;
                int row = idx >> 7, slot = idx & 127;
                *(short8v*)(hlds + row * 1032 + slot * 8) = __builtin_bit_cast(short8v, st[it]);
            }
        }
        __syncthreads();   // [A] hlds ready

        // prefetch next step's gI slice (hides under MFMA phase)
        ushort4 gvn[4] = {};
        if (ks == 0 && b < bsn) {
#pragma unroll
            for (int j = 0; j < 4; ++j)
                gvn[j] = *(const ushort4*)(gI + (size_t)(offn + b) * G4 + (cu0 + 2 * j + hi) * 4);
        }

        // partial gates over this wave's K half: 32x32x16 MFMA chain
        float16v acc;
#pragma unroll
        for (int r = 0; r < 16; ++r) acc[r] = 0.f;
#pragma unroll 8
        for (int kk = 0; kk < 32; ++kk) {
            short8v av = *(const short8v*)(wp + kk * 16);
            short8v bv = *(const short8v*)(hp + kk * 16);
            acc = __builtin_amdgcn_mfma_f32_32x32x16_bf16(av, bv, acc, 0, 0, 0);
        }

        if (ks == 1) {
#pragma unroll
            for (int j = 0; j < 4; ++j) {
                float4 v = make_float4(acc[4 * j], acc[4 * j + 1], acc[4 * j + 2], acc[4 * j + 3]);
                *(float4*)(sgp + j * 8) = v;
            }
        }
        __syncthreads();   // [B] sg ready (also: all hlds reads done)

        bool act = false, retire = false;
        if (ks == 0) {
            act = (b < bs);
            retire = act && (t + 1 >= T || b >= bsn);
#pragma unroll
            for (int j = 0; j < 4; ++j) {
                float4 p = *(const float4*)(sgp + j * 8);
                if (act) {
                    float gi = acc[4 * j + 0] + p.x + bia[j].x + bf2f(gv[j].x);
                    float gf = acc[4 * j + 1] + p.y + bia[j].y + bf2f(gv[j].y);
                    float gg = acc[4 * j + 2] + p.z + bia[j].z + bf2f(gv[j].z);
                    float go = acc[4 * j + 3] + p.w + bia[j].w + bf2f(gv[j].w);
                    float fi = sigm(gi), ff = sigm(gf), fg = tanh_fast(gg), fo = sigm(go);
                    c_reg[j] = ff * c_reg[j] + fi * fg;
                    h_reg[j] = fo * tanh_fast(c_reg[j]);
                }
                gv[j] = gvn[j];
            }
            // publish h: pack (own, partner) bf16 pairs -> ONE 16B IC store
            {
                unsigned wd[4];
#pragma unroll
                for (int j = 0; j < 4; ++j) {
                    float pv = __shfl_xor(h_reg[j], 32);
                    wd[j] = (unsigned)f2bf(h_reg[j]) | ((unsigned)f2bf(pv) << 16);
                }
                if (hi == 0) {
                    int4v pk;
                    pk[0] = (int)wd[0]; pk[1] = (int)wd[1]; pk[2] = (int)wd[2]; pk[3] = (int)wd[3];
                    ic_store16(hn8 + ((size_t)b * 2048 + bid * 32 + ug2 * 16), pk);
                }
            }
        }

        // drain publishes to the coherence point, then signal arrival
        asm volatile("s_waitcnt vmcnt(0)" ::: "memory");
        __builtin_amdgcn_sched_barrier(0);
        __syncthreads();   // [C] whole block's h visible at IC
        unsigned tgt = (unsigned)(t + 1);
        if (t + 1 < T && tid == 0)
            __hip_atomic_store(&flags[bid * 32], tgt, __ATOMIC_RELAXED, __HIP_MEMORY_SCOPE_AGENT);

        // out / hf / cf stores AFTER the signal -> overlap the poll wait
        if (ks == 0 && act) {
            float pv0 = __shfl_xor(h_reg[0], 32);
            float pv1 = __shfl_xor(h_reg[1], 32);
            float pv2 = __shfl_xor(h_reg[2], 32);
            float pv3 = __shfl_xor(h_reg[3], 32);
            if (hi == 0) {
                float* orow = out + (size_t)(off + b) * HID + cu0;
                *(float4*)(orow)     = make_float4(h_reg[0], pv0, h_reg[1], pv1);
                *(float4*)(orow + 4) = make_float4(h_reg[2], pv2, h_reg[3], pv3);
            }
            if (retire) {
#pragma unroll
                for (int j = 0; j < 4; ++j) {
                    int cu = cu0 + 2 * j + hi;
                    hf[b * HID + cu] = h_reg[j];
                    cf[b * HID + cu] = c_reg[j];
                }
            }
        }

        if (t + 1 < T) {
            if (tid < 64) {
                // wave 0: read-only poll of all 64 flag lines, one vector load/round
                for (;;) {
                    unsigned v = __hip_atomic_load(&flags[lane * 32],
                                                   __ATOMIC_RELAXED, __HIP_MEMORY_SCOPE_AGENT);
                    if (__all((int)(v >= tgt))) break;
                    __builtin_amdgcn_s_sleep(1);
                }
            }
            __syncthreads();   // [D] released (block fan-out)
        }
    }
}

extern "C" void kernel_launch(void* const* d_in, const int* in_sizes, int n_in,
                              void* d_out, int out_size, void* d_ws, size_t ws_size,
                              hipStream_t stream)
{
    const float* data = (const float*)d_in[0];
    const int* bs_raw = (const int*)d_in[1];
    const float* Wih = (const float*)d_in[2];
    const float* Whh = (const float*)d_in[3];
    const float* bih = (const float*)d_in[4];
    const float* bhh = (const float*)d_in[5];
    const float* h0 = (const float*)d_in[6];
    const float* c0 = (const float*)d_in[7];
    int total = in_sizes[0] / HID;     // 47872
    int T = in_sizes[1];               // 1000

    char* p = (char*)d_ws;
    unsigned short* gI = (unsigned short*)p;     p += (size_t)total * G4 * 2;
    unsigned short* xb = (unsigned short*)p;     p += (size_t)total * HID * 2;
    unsigned short* wih_r = (unsigned short*)p;  p += (size_t)G4 * HID * 2;
    unsigned short* whh_r = (unsigned short*)p;  p += (size_t)G4 * HID * 2;
    float* bias_r = (float*)p;                   p += (size_t)G4 * 4;
    unsigned short* hbuf0 = (unsigned short*)p;  p += (size_t)BB * HID * 2;
    unsigned short* hbuf1 = (unsigned short*)p;  p += (size_t)BB * HID * 2;
    int* bs_n = (int*)p;                         p += 4096;
    int* offs = (int*)p;                         p += 4096;
    unsigned* bar = (unsigned*)p;                p += 16384;   // 64 flag lines

    float* out = (float*)d_out;
    float* hf = out + (size_t)total * HID;
    float* cf = hf + (size_t)BB * HID;

    prep_kernel<<<4097, 256, 0, stream>>>(data, bs_raw, Wih, Whh, bih, bhh, h0,
                                          xb, wih_r, whh_r, bias_r, hbuf0, hbuf1,
                                          bs_n, offs, bar, total, T);
    gemm_kernel<<<dim3(total / 128, G4 / 128), 256, 0, stream>>>(xb, wih_r, gI);
    lstm_kernel<<<64, 512, 0, stream>>>(gI, whh_r, bias_r, hbuf0, hbuf1, h0, c0,
                                        bs_n, offs, bar, out, hf, cf, T);
}

// Round 7
// 9412.153 us; speedup vs baseline: 1.6743x; 1.4334x over previous
//
#include <hip/hip_runtime.h>
#include <stdint.h>

#define HID 1024
#define G4  4096
#define BB  64

typedef short short8v __attribute__((ext_vector_type(8)));
typedef int   int4v   __attribute__((ext_vector_type(4)));
typedef float float4v __attribute__((ext_vector_type(4)));
typedef float float16v __attribute__((ext_vector_type(16)));
typedef unsigned long long ull;

static __device__ __forceinline__ unsigned short f2bf(float f) {
    unsigned u = __builtin_bit_cast(unsigned, f);
    u += 0x7fffu + ((u >> 16) & 1u);
    return (unsigned short)(u >> 16);
}
static __device__ __forceinline__ float bf2f(unsigned short s) {
    unsigned u = ((unsigned)s) << 16;
    return __builtin_bit_cast(float, u);
}
static __device__ __forceinline__ float sigm(float x) { return 1.0f / (1.0f + __expf(-x)); }
static __device__ __forceinline__ float tanh_fast(float x) { return 2.0f / (1.0f + __expf(-2.0f * x)) - 1.0f; }

// IC-coherent 16B load/store (bypass L1+L2, served at the coherence point).
static __device__ __forceinline__ void ic_load16(const void* p, int4v& d) {
    asm volatile("global_load_dwordx4 %0, %1, off sc0 sc1" : "=v"(d) : "v"(p) : "memory");
}
static __device__ __forceinline__ void ic_store16(void* p, int4v d) {
    asm volatile("global_store_dwordx4 %0, %1, off sc0 sc1" :: "v"(p), "v"(d) : "memory");
}

// ---------------- prep: bf16 converts + unit-major reorder + offsets ----------------
__global__ void prep_kernel(const float* __restrict__ data,
                            const int* __restrict__ bs_raw,
                            const float* __restrict__ Wih, const float* __restrict__ Whh,
                            const float* __restrict__ bih, const float* __restrict__ bhh,
                            const float* __restrict__ h0,
                            unsigned short* __restrict__ xb,
                            unsigned short* __restrict__ wih_r,
                            unsigned short* __restrict__ whh_r,
                            float* __restrict__ bias_r,
                            unsigned short* __restrict__ hb0, unsigned short* __restrict__ hb1,
                            int* __restrict__ bs_n, int* __restrict__ offs,
                            unsigned* __restrict__ bar,
                            int total, int T)
{
    int bid = blockIdx.x, tid = threadIdx.x;
    if (bid == 0) {
        __shared__ int sbs[1024];
        bool is64 = (T > 1) && (bs_raw[1] == 0);   // int64 batch_sizes => low word at 2*t
        for (int t = tid; t < T && t < 1024; t += 256) sbs[t] = is64 ? bs_raw[2 * t] : bs_raw[t];
        // zero the sync region: 2 rows x 64 flag lines (32 dwords apart)
        for (int i = tid; i < 8192; i += 256) bar[i] = 0u;
        __syncthreads();
        if (tid == 0) {
            int acc = 0;
            for (int t = 0; t < T; ++t) { bs_n[t] = sbs[t]; offs[t] = acc; acc += sbs[t]; }
        }
        return;
    }
    long N0 = (long)total * (HID / 4);
    long N1 = N0 + (long)G4 * (HID / 4);
    long N2 = N1 + (long)G4 * (HID / 4);
    long N3 = N2 + G4;
    long N4 = N3 + BB * (HID / 4);
    long stride = (long)(gridDim.x - 1) * 256;
    for (long i = (long)(bid - 1) * 256 + tid; i < N4; i += stride) {
        if (i < N0) {
            float4 d = ((const float4*)data)[i];
            ((ushort4*)xb)[i] = make_ushort4(f2bf(d.x), f2bf(d.y), f2bf(d.z), f2bf(d.w));
        } else if (i < N1) {
            long j = i - N0; int r = (int)(j >> 8); int k4 = (int)(j & 255);
            int u = r >> 2, g = r & 3;
            float4 d = ((const float4*)Wih)[(long)(g * HID + u) * (HID / 4) + k4];
            ((ushort4*)wih_r)[j] = make_ushort4(f2bf(d.x), f2bf(d.y), f2bf(d.z), f2bf(d.w));
        } else if (i < N2) {
            long j = i - N1; int r = (int)(j >> 8); int k4 = (int)(j & 255);
            int u = r >> 2, g = r & 3;
            float4 d = ((const float4*)Whh)[(long)(g * HID + u) * (HID / 4) + k4];
            ((ushort4*)whh_r)[j] = make_ushort4(f2bf(d.x), f2bf(d.y), f2bf(d.z), f2bf(d.w));
        } else if (i < N3) {
            int r = (int)(i - N2); int u = r >> 2, g = r & 3;
            bias_r[r] = bih[g * HID + u] + bhh[g * HID + u];
        } else {
            long j = i - N3;
            float4 d = ((const float4*)h0)[j];
            ushort4 o = make_ushort4(f2bf(d.x), f2bf(d.y), f2bf(d.z), f2bf(d.w));
            ((ushort4*)hb0)[j] = o;
            ((ushort4*)hb1)[j] = o;
        }
    }
}

// ---------------- input GEMM: gI = xb @ wih_r^T  (bf16 out) ----------------
__global__ __launch_bounds__(256) void gemm_kernel(const unsigned short* __restrict__ xb,
                                                   const unsigned short* __restrict__ wr,
                                                   unsigned short* __restrict__ gI)
{
    __shared__ unsigned short As[128 * 32];
    __shared__ unsigned short Bs[128 * 32];
    int tid = threadIdx.x;
    int l = tid & 63;
    int w = tid >> 6;
    int m = l & 15, q = l >> 4;
    int mtile = blockIdx.x, ntile = blockIdx.y;

    const unsigned short* pa = xb + (long)(mtile * 128 + (tid >> 2)) * HID + (tid & 3) * 8;
    const unsigned short* pb = wr + (long)(ntile * 128 + (tid >> 2)) * HID + (tid & 3) * 8;
    unsigned short* la = As + (tid >> 2) * 32 + (tid & 3) * 8;
    unsigned short* lb = Bs + (tid >> 2) * 32 + (tid & 3) * 8;

    int RM = (w >> 1) * 64, CN = (w & 1) * 64;
    float4v acc[4][4];
#pragma unroll
    for (int i = 0; i < 4; ++i)
#pragma unroll
        for (int j = 0; j < 4; ++j) acc[i][j] = (float4v){0.f, 0.f, 0.f, 0.f};

    for (int kt = 0; kt < HID; kt += 32) {
        short8v a0 = *(const short8v*)(pa + kt);
        short8v a1 = *(const short8v*)(pa + 64 * HID + kt);
        short8v b0 = *(const short8v*)(pb + kt);
        short8v b1 = *(const short8v*)(pb + 64 * HID + kt);
        __syncthreads();
        *(short8v*)la = a0;
        *(short8v*)(la + 64 * 32) = a1;
        *(short8v*)lb = b0;
        *(short8v*)(lb + 64 * 32) = b1;
        __syncthreads();
        short8v av[4], bv[4];
#pragma unroll
        for (int i = 0; i < 4; ++i) av[i] = *(const short8v*)&As[(RM + i * 16 + m) * 32 + q * 8];
#pragma unroll
        for (int j = 0; j < 4; ++j) bv[j] = *(const short8v*)&Bs[(CN + j * 16 + m) * 32 + q * 8];
#pragma unroll
        for (int i = 0; i < 4; ++i)
#pragma unroll
            for (int j = 0; j < 4; ++j)
                acc[i][j] = __builtin_amdgcn_mfma_f32_16x16x32_bf16(av[i], bv[j], acc[i][j], 0, 0, 0);
    }
#pragma unroll
    for (int i = 0; i < 4; ++i)
#pragma unroll
        for (int j = 0; j < 4; ++j)
#pragma unroll
            for (int r = 0; r < 4; ++r) {
                int grow = mtile * 128 + RM + i * 16 + q * 4 + r;
                int gcol = ntile * 128 + CN + j * 16 + m;
                gI[(long)grow * G4 + gcol] = f2bf(acc[i][j][r]);
            }
}

// ---------------- persistent recurrent kernel ----------------
// Batch-split restructure: 128 blocks x 512 threads. Block (r = bid>>6,
// j = bid&63) owns batches [32r,+32) x hidden units [16j,+16) = reordered
// gate rows [64j,+64). The recurrence is batch-separable, so block (r,j)
// needs h(t) ONLY for its 32 batches, produced by the 64 blocks of row r:
//   - per-CU IC staging halves (128KB -> 64KB)
//   - the barrier splits into 2 INDEPENDENT 64-producer row barriers
//   - row 1 (batches 32..63) fully retires at t=744 and its blocks EXIT
// 8 waves = 4 K-quarters (ks) x 2 gate-row halves (ug2). 32x32x16 MFMA,
// operand order D = W_tile x h^T (round-4-verified C layout). ks=1..3
// write partials to sg (68-float pitch, measured 0 conflicts); ks=0 sums,
// activates in-register, publishes 16B IC stores. All IC access via
// sc0sc1 dwordx4 (round-6-proven).
__global__ __launch_bounds__(512) void lstm_kernel(
    const unsigned short* __restrict__ gI,
    const unsigned short* __restrict__ whh_r,
    const float* __restrict__ bias_r,
    unsigned short* __restrict__ hb0, unsigned short* __restrict__ hb1,
    const float* __restrict__ h0, const float* __restrict__ c0,
    const int* __restrict__ bs_n, const int* __restrict__ offs,
    unsigned* __restrict__ bar,
    float* __restrict__ out, float* __restrict__ hf, float* __restrict__ cf,
    int T)
{
    __shared__ unsigned short hlds[32 * 1032];   // staged h slice, 66KB (odd 16B-slot pitch)
    __shared__ float sg[3 * 32 * 68];            // ks=1..3 partial gates, 26KB
    __shared__ int sbs[1024], soff[1024];

    int tid = threadIdx.x, bid = blockIdx.x;
    int lane = tid & 63;
    int w = tid >> 6;             // wave 0..7
    int lo5 = lane & 31, hi = lane >> 5;
    int ks = w & 3, ug2 = w >> 2; // K-quarter, gate-row half
    int r = bid >> 6, j = bid & 63;

    unsigned* flags = bar + r * 2048;   // row-r flag lines: 64 x 32-dword stride

    for (int i = tid; i < T && i < 1024; i += 512) { sbs[i] = bs_n[i]; soff[i] = offs[i]; }

    int b = r * 32 + lo5;               // global batch this lane owns (C col)
    int cu_base = j * 16 + ug2 * 8;     // first unit of this wave's 8-unit group
    float c_reg[4], h_reg[4];
    float4 bia[4];
#pragma unroll
    for (int jj = 0; jj < 4; ++jj) {
        int cu = cu_base + 2 * jj + hi;
        c_reg[jj] = c0[b * HID + cu];
        h_reg[jj] = h0[b * HID + cu];
        bia[jj] = *(const float4*)&bias_r[cu * 4];
    }

    // A (W) base: gate rows [64j + 32*ug2, +32), K quarter ks
    const unsigned short* wp = whh_r + (size_t)(j * 64 + ug2 * 32 + lo5) * HID + ks * 256 + hi * 8;
    // B (h^T) base: staged h rows = local batches, K quarter ks
    const unsigned short* hp = hlds + lo5 * 1032 + ks * 256 + hi * 8;
    // sg addresses (region per ks=1..3; 68-float row pitch)
    float* sgw = sg + (ks ? (ks - 1) : 0) * 2176 + lo5 * 68 + ug2 * 32 + hi * 4;
    const float* sgr = sg + lo5 * 68 + ug2 * 32 + hi * 4;

    __syncthreads();

    // gI prefetch pipeline (ks0 lanes): gv = step t, gvn = step t+1
    ushort4 gv[4] = {};
    if (ks == 0 && b < sbs[0]) {
#pragma unroll
        for (int jj = 0; jj < 4; ++jj)
            gv[jj] = *(const ushort4*)(gI + (size_t)(soff[0] + b) * G4 + (cu_base + 2 * jj + hi) * 4);
    }

    for (int t = 0; ; ++t) {
        const char* hq8 = (const char*)((t & 1) ? hb1 : hb0) + (size_t)r * 65536 + (size_t)tid * 16;
        char* hn8 = (char*)((t & 1) ? hb0 : hb1);
        int bs = sbs[t], off = soff[t];
        int bsn = (t + 1 < T) ? sbs[t + 1] : 0;
        int offn = (t + 1 < T) ? soff[t + 1] : 0;

        // stage this row's h slice (64KB): 8 dense 16B IC loads per thread
        {
            int4v st[8];
#pragma unroll
            for (int it = 0; it < 8; ++it)
                ic_load16(hq8 + (size_t)it * 8192, st[it]);
            asm volatile("s_waitcnt vmcnt(0)" ::: "memory");
            __builtin_amdgcn_sched_barrier(0);
#pragma unroll
            for (int it = 0; it < 8; ++it) {
                int idx = it * 512 + tid;
                int row = idx >> 7, slot = idx & 127;
                *(short8v*)(hlds + row * 1032 + slot * 8) = __builtin_bit_cast(short8v, st[it]);
            }
        }
        __syncthreads();   // [A] hlds ready

        // prefetch next step's gI slice (hides under MFMA phase)
        ushort4 gvn[4] = {};
        if (ks == 0 && b < bsn) {
#pragma unroll
            for (int jj = 0; jj < 4; ++jj)
                gvn[jj] = *(const ushort4*)(gI + (size_t)(offn + b) * G4 + (cu_base + 2 * jj + hi) * 4);
        }

        // partial gates over this wave's K quarter: 16 x 32x32x16 MFMA
        float16v acc;
#pragma unroll
        for (int q = 0; q < 16; ++q) acc[q] = 0.f;
#pragma unroll 8
        for (int kk = 0; kk < 16; ++kk) {
            short8v av = *(const short8v*)(wp + kk * 16);
            short8v bv = *(const short8v*)(hp + kk * 16);
            acc = __builtin_amdgcn_mfma_f32_32x32x16_bf16(av, bv, acc, 0, 0, 0);
        }

        if (ks) {
#pragma unroll
            for (int jj = 0; jj < 4; ++jj) {
                float4 v = make_float4(acc[4 * jj], acc[4 * jj + 1], acc[4 * jj + 2], acc[4 * jj + 3]);
                *(float4*)(sgw + jj * 8) = v;
            }
        }
        __syncthreads();   // [B] sg ready (also: all hlds reads done)

        bool last = (t + 1 >= T) || (bsn <= r * 32);   // row fully retired after this step

        bool act = false, retire = false;
        if (ks == 0) {
            act = (b < bs);
            retire = act && (t + 1 >= T || b >= bsn);
#pragma unroll
            for (int jj = 0; jj < 4; ++jj) {
                float4 p1 = *(const float4*)(sgr + 0 * 2176 + jj * 8);
                float4 p2 = *(const float4*)(sgr + 1 * 2176 + jj * 8);
                float4 p3 = *(const float4*)(sgr + 2 * 2176 + jj * 8);
                if (act) {
                    float gi = acc[4 * jj + 0] + p1.x + p2.x + p3.x + bia[jj].x + bf2f(gv[jj].x);
                    float gf = acc[4 * jj + 1] + p1.y + p2.y + p3.y + bia[jj].y + bf2f(gv[jj].y);
                    float gg = acc[4 * jj + 2] + p1.z + p2.z + p3.z + bia[jj].z + bf2f(gv[jj].z);
                    float go = acc[4 * jj + 3] + p1.w + p2.w + p3.w + bia[jj].w + bf2f(gv[jj].w);
                    float fi = sigm(gi), ff = sigm(gf), fg = tanh_fast(gg), fo = sigm(go);
                    c_reg[jj] = ff * c_reg[jj] + fi * fg;
                    h_reg[jj] = fo * tanh_fast(c_reg[jj]);
                }
                gv[jj] = gvn[jj];
            }
            // publish h: pack (own, partner) bf16 pairs -> ONE 16B IC store
            {
                unsigned wd[4];
#pragma unroll
                for (int jj = 0; jj < 4; ++jj) {
                    float pv = __shfl_xor(h_reg[jj], 32);
                    wd[jj] = (unsigned)f2bf(h_reg[jj]) | ((unsigned)f2bf(pv) << 16);
                }
                if (hi == 0) {
                    int4v pk;
                    pk[0] = (int)wd[0]; pk[1] = (int)wd[1]; pk[2] = (int)wd[2]; pk[3] = (int)wd[3];
                    ic_store16(hn8 + ((size_t)b * 2048 + j * 32 + ug2 * 16), pk);
                }
            }
        }

        unsigned tgt = (unsigned)(t + 1);
        if (!last) {
            // drain publishes to the coherence point, then signal arrival
            asm volatile("s_waitcnt vmcnt(0)" ::: "memory");
            __builtin_amdgcn_sched_barrier(0);
            __syncthreads();   // [C] whole block's h visible at IC
            if (tid == 0)
                __hip_atomic_store(&flags[j * 32], tgt, __ATOMIC_RELAXED, __HIP_MEMORY_SCOPE_AGENT);
        }

        // out / hf / cf stores AFTER the signal -> overlap the poll wait
        if (ks == 0 && act) {
            float pv0 = __shfl_xor(h_reg[0], 32);
            float pv1 = __shfl_xor(h_reg[1], 32);
            float pv2 = __shfl_xor(h_reg[2], 32);
            float pv3 = __shfl_xor(h_reg[3], 32);
            if (hi == 0) {
                float* orow = out + (size_t)(off + b) * HID + cu_base;
                *(float4*)(orow)     = make_float4(h_reg[0], pv0, h_reg[1], pv1);
                *(float4*)(orow + 4) = make_float4(h_reg[2], pv2, h_reg[3], pv3);
            }
            if (retire) {
#pragma unroll
                for (int jj = 0; jj < 4; ++jj) {
                    int cu = cu_base + 2 * jj + hi;
                    hf[b * HID + cu] = h_reg[jj];
                    cf[b * HID + cu] = c_reg[jj];
                }
            }
        }

        if (last) break;   // row finished for all remaining steps -> exit

        if (tid < 64) {
            // wave 0: read-only poll of this row's 64 flag lines
            for (;;) {
                unsigned v = __hip_atomic_load(&flags[lane * 32],
                                               __ATOMIC_RELAXED, __HIP_MEMORY_SCOPE_AGENT);
                if (__all((int)(v >= tgt))) break;
                __builtin_amdgcn_s_sleep(1);
            }
        }
        __syncthreads();   // [D] released (block fan-out)
    }
}

extern "C" void kernel_launch(void* const* d_in, const int* in_sizes, int n_in,
                              void* d_out, int out_size, void* d_ws, size_t ws_size,
                              hipStream_t stream)
{
    const float* data = (const float*)d_in[0];
    const int* bs_raw = (const int*)d_in[1];
    const float* Wih = (const float*)d_in[2];
    const float* Whh = (const float*)d_in[3];
    const float* bih = (const float*)d_in[4];
    const float* bhh = (const float*)d_in[5];
    const float* h0 = (const float*)d_in[6];
    const float* c0 = (const float*)d_in[7];
    int total = in_sizes[0] / HID;     // 47872
    int T = in_sizes[1];               // 1000

    char* p = (char*)d_ws;
    unsigned short* gI = (unsigned short*)p;     p += (size_t)total * G4 * 2;
    unsigned short* xb = (unsigned short*)p;     p += (size_t)total * HID * 2;
    unsigned short* wih_r = (unsigned short*)p;  p += (size_t)G4 * HID * 2;
    unsigned short* whh_r = (unsigned short*)p;  p += (size_t)G4 * HID * 2;
    float* bias_r = (float*)p;                   p += (size_t)G4 * 4;
    unsigned short* hbuf0 = (unsigned short*)p;  p += (size_t)BB * HID * 2;
    unsigned short* hbuf1 = (unsigned short*)p;  p += (size_t)BB * HID * 2;
    int* bs_n = (int*)p;                         p += 4096;
    int* offs = (int*)p;                         p += 4096;
    unsigned* bar = (unsigned*)p;                p += 65536;   // 2 rows x 64 flag lines

    float* out = (float*)d_out;
    float* hf = out + (size_t)total * HID;
    float* cf = hf + (size_t)BB * HID;

    prep_kernel<<<4097, 256, 0, stream>>>(data, bs_raw, Wih, Whh, bih, bhh, h0,
                                          xb, wih_r, whh_r, bias_r, hbuf0, hbuf1,
                                          bs_n, offs, bar, total, T);
    gemm_kernel<<<dim3(total / 128, G4 / 128), 256, 0, stream>>>(xb, wih_r, gI);
    lstm_kernel<<<128, 512, 0, stream>>>(gI, whh_r, bias_r, hbuf0, hbuf1, h0, c0,
                                         bs_n, offs, bar, out, hf, cf, T);
}